// Round 1
// baseline (701.198 us; speedup 1.0000x reference)
//
#include <hip/hip_runtime.h>
#include <hip/hip_bf16.h>

// GAT layer: out[i] = sum_{e: src=i} (adj[e] * alpha[e]) * h0[dst[e]],
// alpha = edge-softmax over outgoing edges of src, scores via LeakyReLU(0.05).
// N=100000 nodes, F=128, H=64, E=1.6M edges. All fp32.

#define LEAKY 0.05f

__device__ __forceinline__ float wave_reduce_sum(float v) {
#pragma unroll
    for (int off = 1; off < 64; off <<= 1) v += __shfl_xor(v, off);
    return v;
}

// ---------------------------------------------------------------------------
// K1: h0 = x @ fc_w^T  [N,64]; s_src[i] = h0[i,:]@a_w[:64] + a_b; s_dst = h0@a_w[64:]
// Block 256 = 4 waves; each wave computes 4 nodes; lane = output feature f.
// fc_w staged in LDS as float4 [g=k/4][f] (conflict-free b128 reads).
__global__ __launch_bounds__(256) void k_linear(
    const float* __restrict__ x, const float* __restrict__ fc_w,
    const float* __restrict__ a_w, const float* __restrict__ a_b,
    float* __restrict__ h0, float* __restrict__ s_src, float* __restrict__ s_dst,
    int N)
{
    __shared__ float4 wT[32][64];   // 32 KB: wT[g][f] = fc_w[f][4g..4g+3]
    __shared__ float4 xs[16][32];   // 8 KB: 16 node rows of x (128 f32 each)

    const int tid = threadIdx.x;
    for (int idx = tid; idx < 64 * 32; idx += 256) {
        int f = idx >> 5, g = idx & 31;
        wT[g][f] = *(const float4*)&fc_w[f * 128 + g * 4];
    }

    const int wave = tid >> 6, lane = tid & 63;
    const float aw0 = a_w[lane];
    const float aw1 = a_w[64 + lane];
    const float ab  = a_b[0];

    for (int base = blockIdx.x * 16; base < N; base += gridDim.x * 16) {
        __syncthreads();   // protects xs reuse (and first-iter wT readiness)
        const int nrows = min(16, N - base);
        for (int idx = tid; idx < nrows * 32; idx += 256) {
            int r = idx >> 5, c = idx & 31;
            xs[r][c] = *(const float4*)&x[(size_t)(base + r) * 128 + c * 4];
        }
        __syncthreads();

        const int r0 = wave * 4;
        float acc[4] = {0.f, 0.f, 0.f, 0.f};
#pragma unroll
        for (int g = 0; g < 32; ++g) {
            float4 w = wT[g][lane];
#pragma unroll
            for (int n = 0; n < 4; ++n) {
                float4 xv = xs[r0 + n][g];
                acc[n] += w.x * xv.x + w.y * xv.y + w.z * xv.z + w.w * xv.w;
            }
        }
#pragma unroll
        for (int n = 0; n < 4; ++n) {
            int i = base + r0 + n;
            if (i >= N) break;
            h0[(size_t)i * 64 + lane] = acc[n];
            float p0 = wave_reduce_sum(acc[n] * aw0);
            float p1 = wave_reduce_sum(acc[n] * aw1);
            if (lane == 0) { s_src[i] = p0 + ab; s_dst[i] = p1; }
        }
    }
}

// ---------------------------------------------------------------------------
// K2: degree count
__global__ __launch_bounds__(256) void k_count(
    const int* __restrict__ src, int* __restrict__ deg, int E)
{
    int e = blockIdx.x * 256 + threadIdx.x;
    if (e < E) atomicAdd(&deg[src[e]], 1);
}

// ---------------------------------------------------------------------------
// K3: single-block exclusive scan -> row_ptr[0..N], cursor copy
__global__ __launch_bounds__(1024) void k_scan(
    const int* __restrict__ deg, int* __restrict__ row_ptr,
    int* __restrict__ cursor, int N)
{
    __shared__ int sums[1024];
    const int t = threadIdx.x;
    const int C = (N + 1023) >> 10;
    const int lo = t * C;
    const int hi = min(N, lo + C);

    int s = 0;
    for (int i = lo; i < hi; ++i) s += deg[i];
    sums[t] = s;
    __syncthreads();
#pragma unroll
    for (int off = 1; off < 1024; off <<= 1) {
        int v = (t >= off) ? sums[t - off] : 0;
        __syncthreads();
        sums[t] += v;
        __syncthreads();
    }
    int run = (t == 0) ? 0 : sums[t - 1];
    for (int i = lo; i < hi; ++i) {
        row_ptr[i] = run;
        cursor[i]  = run;
        run += deg[i];
    }
    if (t == 1023) row_ptr[N] = sums[1023];
}

// ---------------------------------------------------------------------------
// K4: scatter edges into CSR order
__global__ __launch_bounds__(256) void k_scatter(
    const int* __restrict__ src, const int* __restrict__ dst,
    const float* __restrict__ adj, int* __restrict__ cursor,
    int* __restrict__ dst_csr, int* __restrict__ eid_csr,
    float* __restrict__ adj_csr, int E)
{
    int e = blockIdx.x * 256 + threadIdx.x;
    if (e >= E) return;
    int s = src[e];
    int pos = atomicAdd(&cursor[s], 1);
    dst_csr[pos] = dst[e];
    eid_csr[pos] = e;
    adj_csr[pos] = adj[e];
}

// ---------------------------------------------------------------------------
// K5: per-node softmax + output accumulation. One wave per node, lane = feature.
__global__ __launch_bounds__(256) void k_node(
    const int* __restrict__ row_ptr, const int* __restrict__ dst_csr,
    const int* __restrict__ eid_csr, const float* __restrict__ adj_csr,
    const float* __restrict__ s_src, const float* __restrict__ s_dst,
    const float* __restrict__ h0, float* __restrict__ out,
    float* __restrict__ alpha_out, int N)
{
    const int wave = threadIdx.x >> 6, lane = threadIdx.x & 63;
    const int i = blockIdx.x * 4 + wave;
    if (i >= N) return;

    const int start = row_ptr[i];
    const int end   = row_ptr[i + 1];
    const float ssrc = s_src[i];   // a_b already folded in

    // pass A: softmax denominator (lane-parallel over edges)
    float part = 0.f;
    for (int j = start + lane; j < end; j += 64) {
        int d = dst_csr[j];
        float t = ssrc + s_dst[d];
        t = (t >= 0.f) ? t : LEAKY * t;
        part += __expf(t);
    }
    part = wave_reduce_sum(part);
    const float inv = 1.0f / part;   // deg==0 -> never used

    // pass B: alpha + gather-accumulate h0[dst]
    float acc = 0.f;
    for (int base = start; base < end; base += 64) {
        const int j = base + lane;
        const int m = min(64, end - base);
        float val = 0.f;
        int d = 0;
        if (j < end) {
            d = dst_csr[j];
            float t = ssrc + s_dst[d];
            t = (t >= 0.f) ? t : LEAKY * t;
            float h = __expf(t);
            float a = h * inv;
            alpha_out[eid_csr[j]] = a;
            val = adj_csr[j] * a;
        }
        for (int jj = 0; jj < m; ++jj) {
            float v  = __shfl(val, jj);
            int   dd = __shfl(d, jj);
            acc += v * h0[(size_t)dd * 64 + lane];
        }
    }
    out[(size_t)i * 64 + lane] = acc;
}

// ---------------------------------------------------------------------------
extern "C" void kernel_launch(void* const* d_in, const int* in_sizes, int n_in,
                              void* d_out, int out_size, void* d_ws, size_t ws_size,
                              hipStream_t stream)
{
    const float* x     = (const float*)d_in[0];
    const int*   ei    = (const int*)d_in[1];   // int64 in reference -> int32 per harness
    const float* adj   = (const float*)d_in[2];
    const float* fc_w  = (const float*)d_in[3];
    const float* a_w   = (const float*)d_in[4];
    const float* a_b   = (const float*)d_in[5];

    const int N = in_sizes[0] / 128;   // 100000
    const int E = in_sizes[2];         // 1600000
    const int* src = ei;
    const int* dst = ei + E;

    float* out   = (float*)d_out;
    float* alpha = out + (size_t)N * 64;

    // workspace carve-up (16B aligned)
    char* w = (char*)d_ws;
    auto carve = [&](size_t bytes) {
        char* p = w;
        w += (bytes + 255) & ~(size_t)255;
        return p;
    };
    float* h0      = (float*)carve((size_t)N * 64 * 4);
    float* s_src   = (float*)carve((size_t)N * 4);
    float* s_dst   = (float*)carve((size_t)N * 4);
    int*   deg     = (int*)  carve((size_t)N * 4);
    int*   row_ptr = (int*)  carve((size_t)(N + 1) * 4);
    int*   cursor  = (int*)  carve((size_t)N * 4);
    int*   dst_csr = (int*)  carve((size_t)E * 4);
    int*   eid_csr = (int*)  carve((size_t)E * 4);
    float* adj_csr = (float*)carve((size_t)E * 4);

    hipMemsetAsync(deg, 0, (size_t)N * 4, stream);

    k_linear<<<2048, 256, 0, stream>>>(x, fc_w, a_w, a_b, h0, s_src, s_dst, N);

    const int egrid = (E + 255) / 256;
    k_count<<<egrid, 256, 0, stream>>>(src, deg, E);
    k_scan<<<1, 1024, 0, stream>>>(deg, row_ptr, cursor, N);
    k_scatter<<<egrid, 256, 0, stream>>>(src, dst, adj, cursor,
                                         dst_csr, eid_csr, adj_csr, E);
    k_node<<<(N + 3) / 4, 256, 0, stream>>>(row_ptr, dst_csr, eid_csr, adj_csr,
                                            s_src, s_dst, h0, out, alpha, N);
}

// Round 2
// 385.980 us; speedup vs baseline: 1.8167x; 1.8167x over previous
//
#include <hip/hip_runtime.h>
#include <hip/hip_bf16.h>

// GAT layer: out[i] = sum_{e: src=i} (adj[e] * alpha[e]) * h0[dst[e]],
// alpha = edge-softmax over outgoing edges of src, scores LeakyReLU(0.05).
// N=100000 nodes, F=128, H=64, E=1.6M edges. All fp32.

#define LEAKY 0.05f

__device__ __forceinline__ float wave_reduce_sum_f(float v) {
#pragma unroll
    for (int off = 1; off < 64; off <<= 1) v += __shfl_xor(v, off);
    return v;
}
__device__ __forceinline__ int wave_reduce_sum_i(int v) {
#pragma unroll
    for (int off = 1; off < 64; off <<= 1) v += __shfl_xor(v, off);
    return v;
}
// inclusive scan within wave
__device__ __forceinline__ int wave_scan_incl(int v, int lane) {
#pragma unroll
    for (int off = 1; off < 64; off <<= 1) {
        int u = __shfl_up(v, off);
        if (lane >= off) v += u;
    }
    return v;
}

// ---------------------------------------------------------------------------
// K1: h0 = x @ fc_w^T [N,64]; s_src[i]=h0[i]@a_w[:64]+a_b; s_dst[i]=h0[i]@a_w[64:]
// 4 waves/block, each wave computes 4 node rows; lane = output feature.
// unroll capped at 4 + launch_bounds(256,4) to avoid the round-1 VGPR spill.
__global__ __launch_bounds__(256, 4) void k_linear(
    const float* __restrict__ x, const float* __restrict__ fc_w,
    const float* __restrict__ a_w, const float* __restrict__ a_b,
    float* __restrict__ h0, float* __restrict__ s_src, float* __restrict__ s_dst,
    int N)
{
    __shared__ float4 wT[32][64];   // 32 KB: wT[g][f] = fc_w[f][4g..4g+3]
    __shared__ float4 xs[16][32];   // 8 KB: 16 node rows of x

    const int tid = threadIdx.x;
    for (int idx = tid; idx < 64 * 32; idx += 256) {
        int f = idx >> 5, g = idx & 31;
        wT[g][f] = *(const float4*)&fc_w[f * 128 + g * 4];
    }

    const int wave = tid >> 6, lane = tid & 63;
    const float aw0 = a_w[lane];
    const float aw1 = a_w[64 + lane];
    const float ab  = a_b[0];

    for (int base = blockIdx.x * 16; base < N; base += gridDim.x * 16) {
        __syncthreads();
        const int nrows = min(16, N - base);
        for (int idx = tid; idx < nrows * 32; idx += 256) {
            int r = idx >> 5, c = idx & 31;
            xs[r][c] = *(const float4*)&x[(size_t)(base + r) * 128 + c * 4];
        }
        __syncthreads();

        const int r0 = wave * 4;
        float acc[4] = {0.f, 0.f, 0.f, 0.f};
#pragma unroll 4
        for (int g = 0; g < 32; ++g) {
            float4 w = wT[g][lane];
#pragma unroll
            for (int n = 0; n < 4; ++n) {
                float4 xv = xs[r0 + n][g];
                acc[n] += w.x * xv.x + w.y * xv.y + w.z * xv.z + w.w * xv.w;
            }
        }
#pragma unroll
        for (int n = 0; n < 4; ++n) {
            int i = base + r0 + n;
            if (i >= N) break;
            h0[(size_t)i * 64 + lane] = acc[n];
            float p0 = wave_reduce_sum_f(acc[n] * aw0);
            float p1 = wave_reduce_sum_f(acc[n] * aw1);
            if (lane == 0) { s_src[i] = p0 + ab; s_dst[i] = p1; }
        }
    }
}

// ---------------------------------------------------------------------------
// K2: degree count
__global__ __launch_bounds__(256) void k_count(
    const int* __restrict__ src, int* __restrict__ deg, int E)
{
    int e = blockIdx.x * 256 + threadIdx.x;
    if (e < E) atomicAdd(&deg[src[e]], 1);
}

// ---------------------------------------------------------------------------
// K3a: per-block partial sums of deg (256 elems/block)
__global__ __launch_bounds__(256) void k_scan_partial(
    const int* __restrict__ deg, int* __restrict__ blk_sum, int N)
{
    __shared__ int ws[4];
    const int i = blockIdx.x * 256 + threadIdx.x;
    const int wave = threadIdx.x >> 6, lane = threadIdx.x & 63;
    int v = (i < N) ? deg[i] : 0;
    v = wave_reduce_sum_i(v);
    if (lane == 0) ws[wave] = v;
    __syncthreads();
    if (threadIdx.x == 0) blk_sum[blockIdx.x] = ws[0] + ws[1] + ws[2] + ws[3];
}

// K3b: single block scans blk_sum[G] -> blk_off[G] (exclusive), chunks of 512
__global__ __launch_bounds__(512) void k_scan_top(
    const int* __restrict__ blk_sum, int* __restrict__ blk_off, int G)
{
    __shared__ int ws[8];
    __shared__ int s_carry;
    const int t = threadIdx.x, wave = t >> 6, lane = t & 63;
    if (t == 0) s_carry = 0;
    __syncthreads();
    for (int base = 0; base < G; base += 512) {
        int idx = base + t;
        int orig = (idx < G) ? blk_sum[idx] : 0;
        int incl = wave_scan_incl(orig, lane);
        if (lane == 63) ws[wave] = incl;
        __syncthreads();
        int woff = 0;
        for (int w = 0; w < wave; ++w) woff += ws[w];
        int carry = s_carry;
        if (idx < G) blk_off[idx] = carry + woff + incl - orig;
        __syncthreads();
        if (t == 511) s_carry = carry + woff + incl;
        __syncthreads();
    }
}

// K3c: final: row_ptr[i] = cursor[i] = blk_off[b] + local exclusive prefix
__global__ __launch_bounds__(256) void k_scan_final(
    const int* __restrict__ deg, const int* __restrict__ blk_off,
    int* __restrict__ row_ptr, int* __restrict__ cursor, int N, int E)
{
    __shared__ int ws[4];
    const int i = blockIdx.x * 256 + threadIdx.x;
    const int wave = threadIdx.x >> 6, lane = threadIdx.x & 63;
    int orig = (i < N) ? deg[i] : 0;
    int incl = wave_scan_incl(orig, lane);
    if (lane == 63) ws[wave] = incl;
    __syncthreads();
    int woff = 0;
    for (int w = 0; w < wave; ++w) woff += ws[w];
    if (i < N) {
        int val = blk_off[blockIdx.x] + woff + incl - orig;
        row_ptr[i] = val;
        cursor[i]  = val;
    }
    if (i == 0) row_ptr[N] = E;
}

// ---------------------------------------------------------------------------
// K4: scatter edges into CSR order; (dst,eid) packed as int2
__global__ __launch_bounds__(256) void k_scatter(
    const int* __restrict__ src, const int* __restrict__ dst,
    const float* __restrict__ adj, int* __restrict__ cursor,
    int2* __restrict__ de_csr, float* __restrict__ adj_csr, int E)
{
    int e = blockIdx.x * 256 + threadIdx.x;
    if (e >= E) return;
    int s = src[e];
    int pos = atomicAdd(&cursor[s], 1);
    de_csr[pos] = make_int2(dst[e], e);
    adj_csr[pos] = adj[e];
}

// ---------------------------------------------------------------------------
// K5: per-node softmax + output accumulation. One wave per node, lane = feature.
__global__ __launch_bounds__(256) void k_node(
    const int* __restrict__ row_ptr, const int2* __restrict__ de_csr,
    const float* __restrict__ adj_csr,
    const float* __restrict__ s_src, const float* __restrict__ s_dst,
    const float* __restrict__ h0, float* __restrict__ out,
    float* __restrict__ alpha_out, int N)
{
    const int wave = threadIdx.x >> 6, lane = threadIdx.x & 63;
    const int i = blockIdx.x * 4 + wave;
    if (i >= N) return;

    const int start = row_ptr[i];
    const int end   = row_ptr[i + 1];
    const float ssrc = s_src[i];   // a_b folded in

    // pass A: softmax denominator
    float part = 0.f;
    for (int j = start + lane; j < end; j += 64) {
        int d = de_csr[j].x;
        float t = ssrc + s_dst[d];
        t = (t >= 0.f) ? t : LEAKY * t;
        part += __expf(t);
    }
    part = wave_reduce_sum_f(part);
    const float inv = 1.0f / part;

    // pass B: alpha + gather-accumulate h0[dst]
    float acc = 0.f;
    for (int base = start; base < end; base += 64) {
        const int j = base + lane;
        const int m = min(64, end - base);
        float val = 0.f;
        int d = 0;
        if (j < end) {
            int2 de = de_csr[j];
            d = de.x;
            float t = ssrc + s_dst[d];
            t = (t >= 0.f) ? t : LEAKY * t;
            float a = __expf(t) * inv;
            alpha_out[de.y] = a;
            val = adj_csr[j] * a;
        }
        for (int jj = 0; jj < m; ++jj) {
            float v  = __shfl(val, jj);
            int   dd = __shfl(d, jj);
            acc += v * h0[(size_t)dd * 64 + lane];
        }
    }
    out[(size_t)i * 64 + lane] = acc;
}

// ---------------------------------------------------------------------------
extern "C" void kernel_launch(void* const* d_in, const int* in_sizes, int n_in,
                              void* d_out, int out_size, void* d_ws, size_t ws_size,
                              hipStream_t stream)
{
    const float* x     = (const float*)d_in[0];
    const int*   ei    = (const int*)d_in[1];
    const float* adj   = (const float*)d_in[2];
    const float* fc_w  = (const float*)d_in[3];
    const float* a_w   = (const float*)d_in[4];
    const float* a_b   = (const float*)d_in[5];

    const int N = in_sizes[0] / 128;   // 100000
    const int E = in_sizes[2];         // 1600000
    const int* src = ei;
    const int* dst = ei + E;

    float* out   = (float*)d_out;
    float* alpha = out + (size_t)N * 64;

    char* w = (char*)d_ws;
    auto carve = [&](size_t bytes) {
        char* p = w;
        w += (bytes + 255) & ~(size_t)255;
        return p;
    };
    float* h0      = (float*)carve((size_t)N * 64 * 4);
    float* s_src   = (float*)carve((size_t)N * 4);
    float* s_dst   = (float*)carve((size_t)N * 4);
    int*   deg     = (int*)  carve((size_t)N * 4);
    int*   row_ptr = (int*)  carve((size_t)(N + 1) * 4);
    int*   cursor  = (int*)  carve((size_t)N * 4);
    int*   blk_sum = (int*)  carve((size_t)((N + 255) / 256) * 4);
    int*   blk_off = (int*)  carve((size_t)((N + 255) / 256) * 4);
    int2*  de_csr  = (int2*) carve((size_t)E * 8);
    float* adj_csr = (float*)carve((size_t)E * 4);

    hipMemsetAsync(deg, 0, (size_t)N * 4, stream);

    k_linear<<<2048, 256, 0, stream>>>(x, fc_w, a_w, a_b, h0, s_src, s_dst, N);

    const int egrid = (E + 255) / 256;
    const int ngrid = (N + 255) / 256;   // 391
    k_count<<<egrid, 256, 0, stream>>>(src, deg, E);
    k_scan_partial<<<ngrid, 256, 0, stream>>>(deg, blk_sum, N);
    k_scan_top<<<1, 512, 0, stream>>>(blk_sum, blk_off, ngrid);
    k_scan_final<<<ngrid, 256, 0, stream>>>(deg, blk_off, row_ptr, cursor, N, E);
    k_scatter<<<egrid, 256, 0, stream>>>(src, dst, adj, cursor, de_csr, adj_csr, E);
    k_node<<<(N + 3) / 4, 256, 0, stream>>>(row_ptr, de_csr, adj_csr,
                                            s_src, s_dst, h0, out, alpha, N);
}